// Round 10
// baseline (356.076 us; speedup 1.0000x reference)
//
#include <hip/hip_runtime.h>
#include <hip/hip_bf16.h>

#define NIN    512
#define NEVAL  1536
#define NCOLS  2048
#define NOUT   256
#define OUT_BASE 1280
#define NBLK   48       // NEVAL / 32
#define RPW    8        // rows per workgroup -> 2 WGs/CU

typedef __attribute__((ext_vector_type(8))) short short8;   // 8 bf16 (4 VGPRs)
typedef __attribute__((ext_vector_type(4))) float floatx4;  // MFMA C/D

// ---------- helpers ----------

__device__ __forceinline__ unsigned short f2bf(float f) {
    __hip_bfloat16 h = __float2bfloat16(f);
    return __builtin_bit_cast(unsigned short, h);
}
__device__ __forceinline__ unsigned pack2(float a, float b) {
    return (unsigned)f2bf(a) | ((unsigned)f2bf(b) << 16);
}
// sigmoid(clip(5z,-60,60)): clamp dropped — v_exp overflow gives exact 0/1.
__device__ __forceinline__ float sigmoid5(float z) {
    return __builtin_amdgcn_rcpf(1.0f + __expf(-5.0f * z));
}

// ---------- W fp32 -> bf16 (d_ws re-poisoned every launch, so rerun) ----------

__global__ __launch_bounds__(256) void wconv(const float* __restrict__ W,
                                             ushort* __restrict__ Wb, int n8) {
    int i = blockIdx.x * blockDim.x + threadIdx.x;
    if (i < n8) {
        float4 v0 = ((const float4*)W)[2 * i];
        float4 v1 = ((const float4*)W)[2 * i + 1];
        uint4 pk;
        pk.x = pack2(v0.x, v0.y); pk.y = pack2(v0.z, v0.w);
        pk.z = pack2(v1.x, v1.y); pk.w = pack2(v1.z, v1.w);
        ((uint4*)Wb)[i] = pk;
    }
}

// ---------- main kernel ----------
// ROUND-10: R9 structure with RPW=8 -> 512 WGs x 512 threads = 2 WGs/CU.
// R9 post-mortem: no pipe saturated (VALU 46%, DS ~45%, MFMA 2.5%) and the
// serial path is ~2.5K of the 12.5K cyc/block -> the wall is dependency
// bubbles in a single per-CU stream. Two independent WGs/CU fill each
// other's barrier/gather/chain bubbles. (R5 tested this pre-R8 when the
// scratch-weight floor masked it — confounded null, hence the retest.)
// Per 32-node block k (columns [L0, L0+32), L0 = 512+32k):
//   stage: diag block -> Wt LDS transposed (Wt[col*33+node])
//   tail:  one K=32 MFMA over [L0-32, L0), owner ksp == (k+3)&3
//   Zred:  8 waves' partials (2 halves x 4 K-splits) -> LDS -> gather
//   main:  MFMAs for block k+1 over [0, L0), K-split 4-way stride 128
//   chain: 32 steps lanes 0-31, readlane broadcast, weights group-prefetched
// A-frag: lane m16 reads O row m16&7 (rows 8-15 duplicate = broadcast, free);
// gather consumes D rows 0..7 only.

__global__ __launch_bounds__(512, 4) void ffnet(const float* __restrict__ x,
                                                const float* __restrict__ W,
                                                const ushort* __restrict__ Wb,
                                                const float* __restrict__ bias,
                                                float* __restrict__ out) {
    __shared__ unsigned short O[RPW * 2048];  // 32 KB
    __shared__ float Zred[8 * 256];           // 8 KB  [wave][lane][reg]
    __shared__ float Wt[32 * 33];             // 4.2 KB diag block, transposed

    const int t    = threadIdx.x;
    const int w    = t >> 6;        // wave 0..7
    const int lane = t & 63;

    // phase-A role
    const int m16  = lane & 15;     // D col (node); A row = m16&7
    const int quad = lane >> 4;     // 0..3
    const int half = w >> 2;        // 0..1
    const int ksp  = w & 3;         // 0..3
    const int arow = (m16 & 7) << 11;
    const int arot = (m16 & 7) << 3;

    // chain role: wave w owns local row w; lanes 0-31 active in the chain
    const int ii   = lane & 31;
    const long row = (long)blockIdx.x * RPW + w;
    const int rot  = w << 3;

    // staging role: two floats of the diag block per thread
    const int sn = t >> 4;          // 0..31 (node within block)
    const int sc = (t & 15) << 1;   // 0,2,..,30 (col pair within block)

    // ---- stage x row w into LDS as bf16 (swizzled) ----
    {
        const float* xr = x + row * NIN + lane * 8;
        float4 v0 = *(const float4*)xr;
        float4 v1 = *(const float4*)(xr + 4);
        uint4 pk;
        pk.x = pack2(v0.x, v0.y); pk.y = pack2(v0.z, v0.w);
        pk.z = pack2(v1.x, v1.y); pk.w = pack2(v1.z, v1.w);
        *(uint4*)&O[(w << 11) + ((lane * 8 + rot) & 2047)] = pk;
    }
    __syncthreads();

    // ---- prologue: main(0) over columns [0, 480), chunks ksp+4t ----
    floatx4 acc = {0.f, 0.f, 0.f, 0.f};
    {
        const ushort* wb = Wb + (size_t)(half * 16 + m16) * NCOLS;
        for (int kk = ksp * 32; kk < NIN - 32; kk += 128) {
            short8 a = *(const short8*)&O[arow + ((kk + quad * 8 + arot) & 2047)];
            short8 b = *(const short8*)&wb[kk + quad * 8];
            acc = __builtin_amdgcn_mfma_f32_16x16x32_bf16(a, b, acc, 0, 0, 0);
        }
    }

    for (int k = 0; k < NBLK; ++k) {
        const int i0 = k << 5;
        const int L0 = NIN + i0;
        const int g  = i0 + ii;     // this lane's eval-node index (mirrored)

        __syncthreads();            // barrier A: chain(k-1) O/Wt-reads done

        // stage diag weights TRANSPOSED: Wt[col*33 + node], 2 cols/thread
        {
            const float* wsrc = &W[(size_t)(i0 + sn) * NCOLS + L0 + sc];
            float2 wv = *(const float2*)wsrc;
            Wt[sc * 33 + sn]       = wv.x;
            Wt[(sc + 1) * 33 + sn] = wv.y;
        }
        float bi = bias[g];

        // tail: K=32 MFMA over [L0-32, L0) — chunk 15+k, owner ksp=(k+3)&3
        if (ksp == ((k + 3) & 3)) {
            const ushort* wb = Wb + (size_t)(i0 + half * 16 + m16) * NCOLS;
            const int ts = L0 - 32;
            short8 a = *(const short8*)&O[arow + ((ts + quad * 8 + arot) & 2047)];
            short8 b = *(const short8*)&wb[ts + quad * 8];
            acc = __builtin_amdgcn_mfma_f32_16x16x32_bf16(a, b, acc, 0, 0, 0);
        }

        // D frag: lane q*16+n holds Z[m=4q+reg][n]
        *(floatx4*)&Zred[(w << 8) + (lane << 2)] = acc;
        __syncthreads();            // barrier B: Zred + Wt visible

        // gather z for (row w, node ii): sum 4 K-split partials
        const int h = ii >> 4, n = ii & 15;
        const int ridx = ((w >> 2) << 6) + (n << 2) + (w & 3);
        float zacc = bi;
        #pragma unroll
        for (int p = 0; p < 4; ++p)
            zacc += Zred[(((h << 2) + p) << 8) + ridx];

        // prefetch weight group 0 (steps 0-3)
        float wa0 = Wt[ 0 * 33 + ii], wa1 = Wt[ 1 * 33 + ii],
              wa2 = Wt[ 2 * 33 + ii], wa3 = Wt[ 3 * 33 + ii];

        // issue main(k+1) over [0, L0)
        floatx4 accN = {0.f, 0.f, 0.f, 0.f};
        if (k + 1 < NBLK) {
            const ushort* wb = Wb + (size_t)(i0 + 32 + half * 16 + m16) * NCOLS;
            #pragma unroll 4
            for (int kk = ksp * 32; kk < L0; kk += 128) {
                short8 a = *(const short8*)&O[arow + ((kk + quad * 8 + arot) & 2047)];
                short8 b = *(const short8*)&wb[kk + quad * 8];
                accN = __builtin_amdgcn_mfma_f32_16x16x32_bf16(a, b, accN, 0, 0, 0);
            }
        }

        // chain: 32 sequential sigmoid steps, lanes 0-31, weights group-
        // prefetched from LDS (double-buffered groups of 4).
        if (lane < 32) {
            #define STEP(JJ, WV)                                               \
                {                                                              \
                    float zj = __builtin_bit_cast(float,                       \
                        __builtin_amdgcn_readlane(                             \
                            __builtin_bit_cast(int, zacc), JJ));               \
                    zacc = fmaf(WV, sigmoid5(zj), zacc);                       \
                }
            float wb0 = Wt[ 4 * 33 + ii], wb1 = Wt[ 5 * 33 + ii],
                  wb2 = Wt[ 6 * 33 + ii], wb3 = Wt[ 7 * 33 + ii];
            STEP( 0, wa0) STEP( 1, wa1) STEP( 2, wa2) STEP( 3, wa3)
            wa0 = Wt[ 8 * 33 + ii]; wa1 = Wt[ 9 * 33 + ii];
            wa2 = Wt[10 * 33 + ii]; wa3 = Wt[11 * 33 + ii];
            STEP( 4, wb0) STEP( 5, wb1) STEP( 6, wb2) STEP( 7, wb3)
            wb0 = Wt[12 * 33 + ii]; wb1 = Wt[13 * 33 + ii];
            wb2 = Wt[14 * 33 + ii]; wb3 = Wt[15 * 33 + ii];
            STEP( 8, wa0) STEP( 9, wa1) STEP(10, wa2) STEP(11, wa3)
            wa0 = Wt[16 * 33 + ii]; wa1 = Wt[17 * 33 + ii];
            wa2 = Wt[18 * 33 + ii]; wa3 = Wt[19 * 33 + ii];
            STEP(12, wb0) STEP(13, wb1) STEP(14, wb2) STEP(15, wb3)
            wb0 = Wt[20 * 33 + ii]; wb1 = Wt[21 * 33 + ii];
            wb2 = Wt[22 * 33 + ii]; wb3 = Wt[23 * 33 + ii];
            STEP(16, wa0) STEP(17, wa1) STEP(18, wa2) STEP(19, wa3)
            wa0 = Wt[24 * 33 + ii]; wa1 = Wt[25 * 33 + ii];
            wa2 = Wt[26 * 33 + ii]; wa3 = Wt[27 * 33 + ii];
            STEP(20, wb0) STEP(21, wb1) STEP(22, wb2) STEP(23, wb3)
            wb0 = Wt[28 * 33 + ii]; wb1 = Wt[29 * 33 + ii];
            wb2 = Wt[30 * 33 + ii]; wb3 = Wt[31 * 33 + ii];
            STEP(24, wa0) STEP(25, wa1) STEP(26, wa2) STEP(27, wa3)
            STEP(28, wb0) STEP(29, wb1) STEP(30, wb2) STEP(31, wb3)
            #undef STEP
            float o = sigmoid5(zacc);

            O[(w << 11) + ((L0 + ii + rot) & 2047)] = f2bf(o);
            if (g >= OUT_BASE)
                out[row * NOUT + (g - OUT_BASE)] = o;
        }
        acc = accN;
    }
}

// ---------- launch ----------

extern "C" void kernel_launch(void* const* d_in, const int* in_sizes, int n_in,
                              void* d_out, int out_size, void* d_ws, size_t ws_size,
                              hipStream_t stream) {
    const float* x  = (const float*)d_in[0];   // [4096, 512]
    const float* W  = (const float*)d_in[1];   // [1536, 2048]
    const float* b  = (const float*)d_in[2];   // [1536]
    float* out = (float*)d_out;                // [4096, 256]
    ushort* Wb = (ushort*)d_ws;                // bf16 W copy (6.3 MB)

    int n8 = NEVAL * NCOLS / 8;
    wconv<<<n8 / 256, 256, 0, stream>>>(W, Wb, n8);
    ffnet<<<4096 / RPW, 512, 0, stream>>>(x, W, Wb, b, out);
}

// Round 11
// 317.562 us; speedup vs baseline: 1.1213x; 1.1213x over previous
//
#include <hip/hip_runtime.h>
#include <hip/hip_bf16.h>

#define NIN    512
#define NEVAL  1536
#define NCOLS  2048
#define NOUT   256
#define OUT_BASE 1280
#define NBLK   48       // NEVAL / 32

typedef __attribute__((ext_vector_type(8))) short short8;   // 8 bf16 (4 VGPRs)
typedef __attribute__((ext_vector_type(4))) float floatx4;  // MFMA C/D

// ---------- helpers ----------

__device__ __forceinline__ unsigned short f2bf(float f) {
    __hip_bfloat16 h = __float2bfloat16(f);
    return __builtin_bit_cast(unsigned short, h);
}
__device__ __forceinline__ unsigned pack2(float a, float b) {
    return (unsigned)f2bf(a) | ((unsigned)f2bf(b) << 16);
}
// sigmoid(clip(5z,-60,60)): clamp dropped — v_exp overflow gives exact 0/1.
__device__ __forceinline__ float sigmoid5(float z) {
    return __builtin_amdgcn_rcpf(1.0f + __expf(-5.0f * z));
}

// ---------- W fp32 -> bf16 (d_ws re-poisoned every launch, so rerun) ----------

__global__ __launch_bounds__(256) void wconv(const float* __restrict__ W,
                                             ushort* __restrict__ Wb, int n8) {
    int i = blockIdx.x * blockDim.x + threadIdx.x;
    if (i < n8) {
        float4 v0 = ((const float4*)W)[2 * i];
        float4 v1 = ((const float4*)W)[2 * i + 1];
        uint4 pk;
        pk.x = pack2(v0.x, v0.y); pk.y = pack2(v0.z, v0.w);
        pk.z = pack2(v1.x, v1.y); pk.w = pack2(v1.z, v1.w);
        ((uint4*)Wb)[i] = pk;
    }
}

// ---------- main kernel ----------
// 256 WGs x 1024 threads (16 waves), 1 WG/CU. WG owns 16 rows; wave w = row w.
// O[16][2048] bf16 in LDS, row r rotated by 8r elements.
// ROUND-11 per-block order (vs R9): main(k+1) is issued IMMEDIATELY after
// barrier A — its load->MFMA waitcnt stalls overlap the Wt global load, the
// tail, and the barrier-B convergence wait (where waves idled anyway),
// instead of sitting serially between gather and chain (in-order issue made
// every wave drain ~1.2K cyc of L2/LDS latency before its chain could start).
// Legal: main(k+1) reads O[0, L0) only, final since chain(k-1)/barrier A.
// unroll 4 keeps 4 iterations' loads in flight (VGPR headroom: 52->~128 ok
// at 4 waves/SIMD).
//   stage: diag block -> Wt LDS transposed (Wt[col*33+node])
//   tail:  one K=32 MFMA over [L0-32, L0), owner ksp == (k+7)&7
//   Zred:  16 waves' partials -> LDS -> gather (8 K-split partials)
//   chain: 32 steps lanes 0-31, readlane broadcast, weights group-prefetched

__global__ __launch_bounds__(1024) void ffnet(const float* __restrict__ x,
                                              const float* __restrict__ W,
                                              const ushort* __restrict__ Wb,
                                              const float* __restrict__ bias,
                                              float* __restrict__ out) {
    __shared__ unsigned short O[16 * 2048];   // 64 KB
    __shared__ float Zred[16 * 256];          // 16 KB  [wave][lane][reg]
    __shared__ float Wt[32 * 33];             // 4.2 KB diag block, transposed

    const int t    = threadIdx.x;
    const int w    = t >> 6;        // wave 0..15
    const int lane = t & 63;

    // phase-A role
    const int m16  = lane & 15;     // A row (batch row) / D col (node)
    const int quad = lane >> 4;     // 0..3
    const int half = w >> 3;        // 0..1
    const int ksp  = w & 7;         // 0..7
    const int arow = m16 << 11;
    const int arot = m16 << 3;

    // chain role: wave w owns local row w; lanes 0-31 active in the chain
    const int ii   = lane & 31;
    const long row = (long)blockIdx.x * 16 + w;
    const int rot  = w << 3;

    // staging role: one float of the diag block per thread
    const int sn = t >> 5;          // 0..31 (node within block)
    const int sc = t & 31;          // 0..31 (col within block)

    // ---- stage x row w into LDS as bf16 (swizzled) ----
    {
        const float* xr = x + row * NIN + lane * 8;
        float4 v0 = *(const float4*)xr;
        float4 v1 = *(const float4*)(xr + 4);
        uint4 pk;
        pk.x = pack2(v0.x, v0.y); pk.y = pack2(v0.z, v0.w);
        pk.z = pack2(v1.x, v1.y); pk.w = pack2(v1.z, v1.w);
        *(uint4*)&O[(w << 11) + ((lane * 8 + rot) & 2047)] = pk;
    }
    __syncthreads();

    // ---- prologue: main(0) over columns [0, 480) ----
    floatx4 acc = {0.f, 0.f, 0.f, 0.f};
    {
        const ushort* wb = Wb + (size_t)(half * 16 + m16) * NCOLS;
        for (int kk = ksp * 32; kk < NIN - 32; kk += 256) {
            short8 a = *(const short8*)&O[arow + ((kk + quad * 8 + arot) & 2047)];
            short8 b = *(const short8*)&wb[kk + quad * 8];
            acc = __builtin_amdgcn_mfma_f32_16x16x32_bf16(a, b, acc, 0, 0, 0);
        }
    }

    for (int k = 0; k < NBLK; ++k) {
        const int i0 = k << 5;
        const int L0 = NIN + i0;
        const int g  = i0 + ii;     // this lane's eval-node index (mirrored)

        __syncthreads();            // barrier A: chain(k-1) O/Wt-reads done

        // issue Wt global load + bias early (consumed below, after main issue)
        float wtv = W[(size_t)(i0 + sn) * NCOLS + L0 + sc];
        float bi  = bias[g];

        // issue main(k+1) over [0, L0) NOW — stalls overlap Wt load + tail +
        // barrier-B wait instead of preceding the chain.
        floatx4 accN = {0.f, 0.f, 0.f, 0.f};
        if (k + 1 < NBLK) {
            const ushort* wb = Wb + (size_t)(i0 + 32 + half * 16 + m16) * NCOLS;
            #pragma unroll 4
            for (int kk = ksp * 32; kk < L0; kk += 256) {
                short8 a = *(const short8*)&O[arow + ((kk + quad * 8 + arot) & 2047)];
                short8 b = *(const short8*)&wb[kk + quad * 8];
                accN = __builtin_amdgcn_mfma_f32_16x16x32_bf16(a, b, accN, 0, 0, 0);
            }
        }

        // stage diag weights TRANSPOSED: Wt[col*33 + node]
        Wt[sc * 33 + sn] = wtv;

        // tail: K=32 MFMA over [L0-32, L0) — chunk 15+k, owner ksp=(k+7)&7
        if (ksp == ((k + 7) & 7)) {
            const ushort* wb = Wb + (size_t)(i0 + half * 16 + m16) * NCOLS;
            const int ts = L0 - 32;
            short8 a = *(const short8*)&O[arow + ((ts + quad * 8 + arot) & 2047)];
            short8 b = *(const short8*)&wb[ts + quad * 8];
            acc = __builtin_amdgcn_mfma_f32_16x16x32_bf16(a, b, acc, 0, 0, 0);
        }

        // D frag: lane q*16+n holds Z[m=4q+reg][n]
        *(floatx4*)&Zred[(w << 8) + (lane << 2)] = acc;
        __syncthreads();            // barrier B: Zred + Wt visible

        // gather z for (row w, node ii): sum 8 K-split partials
        const int h = ii >> 4, n = ii & 15;
        const int ridx = ((w >> 2) << 6) + (n << 2) + (w & 3);
        float zacc = bi;
        #pragma unroll
        for (int p = 0; p < 8; ++p)
            zacc += Zred[(((h << 3) + p) << 8) + ridx];

        // prefetch weight group 0 (steps 0-3)
        float wa0 = Wt[ 0 * 33 + ii], wa1 = Wt[ 1 * 33 + ii],
              wa2 = Wt[ 2 * 33 + ii], wa3 = Wt[ 3 * 33 + ii];

        // chain: 32 sequential sigmoid steps, lanes 0-31, weights group-
        // prefetched from LDS (double-buffered groups of 4).
        if (lane < 32) {
            #define STEP(JJ, WV)                                               \
                {                                                              \
                    float zj = __builtin_bit_cast(float,                       \
                        __builtin_amdgcn_readlane(                             \
                            __builtin_bit_cast(int, zacc), JJ));               \
                    zacc = fmaf(WV, sigmoid5(zj), zacc);                       \
                }
            float wb0 = Wt[ 4 * 33 + ii], wb1 = Wt[ 5 * 33 + ii],
                  wb2 = Wt[ 6 * 33 + ii], wb3 = Wt[ 7 * 33 + ii];
            STEP( 0, wa0) STEP( 1, wa1) STEP( 2, wa2) STEP( 3, wa3)
            wa0 = Wt[ 8 * 33 + ii]; wa1 = Wt[ 9 * 33 + ii];
            wa2 = Wt[10 * 33 + ii]; wa3 = Wt[11 * 33 + ii];
            STEP( 4, wb0) STEP( 5, wb1) STEP( 6, wb2) STEP( 7, wb3)
            wb0 = Wt[12 * 33 + ii]; wb1 = Wt[13 * 33 + ii];
            wb2 = Wt[14 * 33 + ii]; wb3 = Wt[15 * 33 + ii];
            STEP( 8, wa0) STEP( 9, wa1) STEP(10, wa2) STEP(11, wa3)
            wa0 = Wt[16 * 33 + ii]; wa1 = Wt[17 * 33 + ii];
            wa2 = Wt[18 * 33 + ii]; wa3 = Wt[19 * 33 + ii];
            STEP(12, wb0) STEP(13, wb1) STEP(14, wb2) STEP(15, wb3)
            wb0 = Wt[20 * 33 + ii]; wb1 = Wt[21 * 33 + ii];
            wb2 = Wt[22 * 33 + ii]; wb3 = Wt[23 * 33 + ii];
            STEP(16, wa0) STEP(17, wa1) STEP(18, wa2) STEP(19, wa3)
            wa0 = Wt[24 * 33 + ii]; wa1 = Wt[25 * 33 + ii];
            wa2 = Wt[26 * 33 + ii]; wa3 = Wt[27 * 33 + ii];
            STEP(20, wb0) STEP(21, wb1) STEP(22, wb2) STEP(23, wb3)
            wb0 = Wt[28 * 33 + ii]; wb1 = Wt[29 * 33 + ii];
            wb2 = Wt[30 * 33 + ii]; wb3 = Wt[31 * 33 + ii];
            STEP(24, wa0) STEP(25, wa1) STEP(26, wa2) STEP(27, wa3)
            STEP(28, wb0) STEP(29, wb1) STEP(30, wb2) STEP(31, wb3)
            #undef STEP
            float o = sigmoid5(zacc);

            O[(w << 11) + ((L0 + ii + rot) & 2047)] = f2bf(o);
            if (g >= OUT_BASE)
                out[row * NOUT + (g - OUT_BASE)] = o;
        }
        acc = accN;
    }
}

// ---------- launch ----------

extern "C" void kernel_launch(void* const* d_in, const int* in_sizes, int n_in,
                              void* d_out, int out_size, void* d_ws, size_t ws_size,
                              hipStream_t stream) {
    const float* x  = (const float*)d_in[0];   // [4096, 512]
    const float* W  = (const float*)d_in[1];   // [1536, 2048]
    const float* b  = (const float*)d_in[2];   // [1536]
    float* out = (float*)d_out;                // [4096, 256]
    ushort* Wb = (ushort*)d_ws;                // bf16 W copy (6.3 MB)

    int n8 = NEVAL * NCOLS / 8;
    wconv<<<n8 / 256, 256, 0, stream>>>(W, Wb, n8);
    ffnet<<<4096 / 16, 1024, 0, stream>>>(x, W, Wb, b, out);
}

// Round 12
// 295.516 us; speedup vs baseline: 1.2049x; 1.0746x over previous
//
#include <hip/hip_runtime.h>
#include <hip/hip_bf16.h>

#define NIN    512
#define NEVAL  1536
#define NCOLS  2048
#define NOUT   256
#define OUT_BASE 1280
#define BK     64
#define NBLK   24       // NEVAL / BK

typedef __attribute__((ext_vector_type(8))) short short8;   // 8 bf16 (4 VGPRs)
typedef __attribute__((ext_vector_type(4))) float floatx4;  // MFMA C/D

// ---------- helpers ----------

__device__ __forceinline__ unsigned short f2bf(float f) {
    __hip_bfloat16 h = __float2bfloat16(f);
    return __builtin_bit_cast(unsigned short, h);
}
__device__ __forceinline__ unsigned pack2(float a, float b) {
    return (unsigned)f2bf(a) | ((unsigned)f2bf(b) << 16);
}
// sigmoid(clip(5z,-60,60)): clamp dropped — v_exp overflow gives exact 0/1.
__device__ __forceinline__ float sigmoid5(float z) {
    return __builtin_amdgcn_rcpf(1.0f + __expf(-5.0f * z));
}

// ---------- W fp32 -> bf16 (d_ws re-poisoned every launch, so rerun) ----------

__global__ __launch_bounds__(256) void wconv(const float* __restrict__ W,
                                             ushort* __restrict__ Wb, int n8) {
    int i = blockIdx.x * blockDim.x + threadIdx.x;
    if (i < n8) {
        float4 v0 = ((const float4*)W)[2 * i];
        float4 v1 = ((const float4*)W)[2 * i + 1];
        uint4 pk;
        pk.x = pack2(v0.x, v0.y); pk.y = pack2(v0.z, v0.w);
        pk.z = pack2(v1.x, v1.y); pk.w = pack2(v1.z, v1.w);
        ((uint4*)Wb)[i] = pk;
    }
}

// ---------- main kernel ----------
// 256 WGs x 1024 threads (16 waves), 1 WG/CU. WG owns 16 rows; wave w = row w
// for the chain. O[16][2048] bf16 in LDS, row r rotated by 8r elements.
// ROUND-12: BK=64 (NBLK 48->24). R8-R11 showed time is pinned by per-block
// FIXED costs (2 barrier convergences, W-diag load drain, gather latency,
// main waitcnt drains) — not by pipes (VALU 45%, MFMA 2.4%) nor stream count
// (R10 regressed) nor in-block order (R11 neutral). Halving the block count
// halves the number of fixed-cost instances; total chain steps (1536) and
// total MFMA work unchanged.
// Phase-A roles: 4 node-groups (w>>2) x 4 K-split slots (w&3, stride 128).
// Per 64-node block k (cols [L0, L0+64), L0 = 512+64k):
//   Wt:    64x64 diag block -> LDS transposed (Wt[col*65+node]), 4 flt/thread
//   main:  MFMAs for block k+1 over [0, L0) — issued right after barrier A
//   tail:  2 K=32 MFMAs over [L0-64, L0): chunk 14+2k owner (2k+2)&3,
//          chunk 15+2k owner (2k+3)&3 (per node-group)
//   Zred:  16 waves' D frags -> LDS; gather sums 4 K-split partials
//   chain: 64 steps, ALL 64 lanes (node ii = lane), readlane broadcast,
//          per-step Wt[jj*65+ii] read (R9 prefetch was neutral vs this)

__global__ __launch_bounds__(1024) void ffnet(const float* __restrict__ x,
                                              const float* __restrict__ W,
                                              const ushort* __restrict__ Wb,
                                              const float* __restrict__ bias,
                                              float* __restrict__ out) {
    __shared__ unsigned short O[16 * 2048];   // 64 KB
    __shared__ float Zred[16 * 256];          // 16 KB  [wave][lane][reg]
    __shared__ float Wt[64 * 65];             // 16.6 KB diag block, transposed

    const int t    = threadIdx.x;
    const int w    = t >> 6;        // wave 0..15
    const int lane = t & 63;

    // phase-A role
    const int m16  = lane & 15;     // A row (batch row) / D col (node in group)
    const int quad = lane >> 4;     // 0..3
    const int ng   = w >> 2;        // node group 0..3 (16 nodes each)
    const int ksp  = w & 3;         // K-split slot, stride 128
    const int arow = m16 << 11;
    const int arot = m16 << 3;

    // chain role: wave w owns local row w; node ii = lane (0..63)
    const int ii   = lane;
    const long row = (long)blockIdx.x * 16 + w;
    const int rot  = w << 3;

    // Wt staging role: node sn (0..63), col group sc (0,4,..,60)
    const int sn = t >> 4;
    const int sc = (t & 15) << 2;

    // ---- stage x row w into LDS as bf16 (swizzled) ----
    {
        const float* xr = x + row * NIN + lane * 8;
        float4 v0 = *(const float4*)xr;
        float4 v1 = *(const float4*)(xr + 4);
        uint4 pk;
        pk.x = pack2(v0.x, v0.y); pk.y = pack2(v0.z, v0.w);
        pk.z = pack2(v1.x, v1.y); pk.w = pack2(v1.z, v1.w);
        *(uint4*)&O[(w << 11) + ((lane * 8 + rot) & 2047)] = pk;
    }
    __syncthreads();

    // ---- prologue: main(0) over columns [0, 448) (chunks 0..13) ----
    floatx4 acc = {0.f, 0.f, 0.f, 0.f};
    {
        const ushort* wb = Wb + (size_t)(ng * 16 + m16) * NCOLS;
        for (int kk = ksp * 32; kk < NIN - BK; kk += 128) {
            short8 a = *(const short8*)&O[arow + ((kk + quad * 8 + arot) & 2047)];
            short8 b = *(const short8*)&wb[kk + quad * 8];
            acc = __builtin_amdgcn_mfma_f32_16x16x32_bf16(a, b, acc, 0, 0, 0);
        }
    }

    for (int k = 0; k < NBLK; ++k) {
        const int i0 = k << 6;
        const int L0 = NIN + i0;
        const int g  = i0 + ii;     // this lane's eval-node index

        __syncthreads();            // barrier A: chain(k-1) O/Wt-reads done

        // issue Wt diag load (4 floats/thread) + bias early
        float4 wtv = *(const float4*)&W[(size_t)(i0 + sn) * NCOLS + L0 + sc];
        float bi   = bias[g];

        // issue main(k+1) over [0, L0) — drains overlap Wt stage + barrier B
        floatx4 accN = {0.f, 0.f, 0.f, 0.f};
        if (k + 1 < NBLK) {
            const ushort* wb = Wb + (size_t)(i0 + BK + ng * 16 + m16) * NCOLS;
            #pragma unroll 4
            for (int kk = ksp * 32; kk < L0; kk += 128) {
                short8 a = *(const short8*)&O[arow + ((kk + quad * 8 + arot) & 2047)];
                short8 b = *(const short8*)&wb[kk + quad * 8];
                accN = __builtin_amdgcn_mfma_f32_16x16x32_bf16(a, b, accN, 0, 0, 0);
            }
        }

        // stage diag weights TRANSPOSED: Wt[col*65 + node]
        Wt[(sc + 0) * 65 + sn] = wtv.x;
        Wt[(sc + 1) * 65 + sn] = wtv.y;
        Wt[(sc + 2) * 65 + sn] = wtv.z;
        Wt[(sc + 3) * 65 + sn] = wtv.w;

        // tail: 2 K=32 MFMAs over [L0-64, L0) — chunks 14+2k / 15+2k,
        // owners (2k+2)&3 / (2k+3)&3 per node-group.
        {
            const ushort* wb = Wb + (size_t)(i0 + ng * 16 + m16) * NCOLS;
            if (ksp == ((2 * k + 2) & 3)) {
                const int ts = L0 - 64;
                short8 a = *(const short8*)&O[arow + ((ts + quad * 8 + arot) & 2047)];
                short8 b = *(const short8*)&wb[ts + quad * 8];
                acc = __builtin_amdgcn_mfma_f32_16x16x32_bf16(a, b, acc, 0, 0, 0);
            }
            if (ksp == ((2 * k + 3) & 3)) {
                const int ts = L0 - 32;
                short8 a = *(const short8*)&O[arow + ((ts + quad * 8 + arot) & 2047)];
                short8 b = *(const short8*)&wb[ts + quad * 8];
                acc = __builtin_amdgcn_mfma_f32_16x16x32_bf16(a, b, acc, 0, 0, 0);
            }
        }

        // D frag: lane q*16+n holds Z[m=4q+reg][n]
        *(floatx4*)&Zred[(w << 8) + (lane << 2)] = acc;
        __syncthreads();            // barrier B: Zred + Wt visible

        // gather z for (row w, node ii): sum 4 K-split partials of group h
        const int h = ii >> 4, n = ii & 15;
        const int ridx = ((w >> 2) << 6) + (n << 2) + (w & 3);
        float zacc = bi;
        #pragma unroll
        for (int p = 0; p < 4; ++p)
            zacc += Zred[(((h << 2) + p) << 8) + ridx];

        // chain: 64 sequential sigmoid steps, all 64 lanes.
        // Wt[jj*65+ii] == 0 for jj >= ii (strictly lower-triangular).
        #pragma unroll
        for (int jj = 0; jj < BK; ++jj) {
            float zj = __builtin_bit_cast(float,
                __builtin_amdgcn_readlane(__builtin_bit_cast(int, zacc), jj));
            zacc = fmaf(Wt[jj * 65 + ii], sigmoid5(zj), zacc);
        }
        float o = sigmoid5(zacc);

        O[(w << 11) + ((L0 + ii + rot) & 2047)] = f2bf(o);
        if (g >= OUT_BASE)
            out[row * NOUT + (g - OUT_BASE)] = o;

        acc = accN;
    }
}

// ---------- launch ----------

extern "C" void kernel_launch(void* const* d_in, const int* in_sizes, int n_in,
                              void* d_out, int out_size, void* d_ws, size_t ws_size,
                              hipStream_t stream) {
    const float* x  = (const float*)d_in[0];   // [4096, 512]
    const float* W  = (const float*)d_in[1];   // [1536, 2048]
    const float* b  = (const float*)d_in[2];   // [1536]
    float* out = (float*)d_out;                // [4096, 256]
    ushort* Wb = (ushort*)d_ws;                // bf16 W copy (6.3 MB)

    int n8 = NEVAL * NCOLS / 8;
    wconv<<<n8 / 256, 256, 0, stream>>>(W, Wb, n8);
    ffnet<<<4096 / 16, 1024, 0, stream>>>(x, W, Wb, b, out);
}